// Round 2
// baseline (168.386 us; speedup 1.0000x reference)
//
#include <hip/hip_runtime.h>
#include <hip/hip_fp16.h>

// SilkNNUE R13 — int8 embedding table: halve L2 gather bytes AND requests.
//   R12 evidence: occupancy 46->56% with dur unchanged => gather is
//   throughput-bound on the L2 path (1.07 GB @ 20.4 TB/s effective).
//   Fix: quantize emb to u8 (bias +128, device-computed absmax scale,
//   robust to re-poison). 128B/row -> 4 loads/row (was 8), half the 64B
//   L2 requests. Byte order per 4-dim group is (d0,d2,d1,d3) so masked
//   u32 adds accumulate ADJACENT dim pairs in 16-bit slots (max 8160).
//   8 lanes/feature, xor-butterfly allreduce over 8 f-groups, then all
//   64 lanes convert one dim-pair (cndmask select, no runtime indexing)
//   and ds_write_b32 into the same swizzled hT layout. MFMA unchanged.
// Chain: memset(amax) -> emb_absmax -> prep_q8 -> nnue_one_q8.

typedef _Float16 h2v_t  __attribute__((ext_vector_type(2)));
typedef _Float16 half8  __attribute__((ext_vector_type(8)));
typedef float    f32x4  __attribute__((ext_vector_type(4)));

constexpr int RPB = 64;   // rows per block

// ---- absmax over emb (950272 floats) --------------------------------------
__global__ __launch_bounds__(256) void emb_absmax(
    const float4* __restrict__ emb4, unsigned* __restrict__ amax, int n4)
{
    int i = blockIdx.x * blockDim.x + threadIdx.x;
    float m = 0.f;
    if (i < n4) {
        float4 v = emb4[i];
        m = fmaxf(fmaxf(fabsf(v.x), fabsf(v.y)), fmaxf(fabsf(v.z), fabsf(v.w)));
    }
    #pragma unroll
    for (int s = 1; s < 64; s <<= 1)
        m = fmaxf(m, __shfl_xor(m, s));
    if ((threadIdx.x & 63) == 0)
        atomicMax(amax, __builtin_bit_cast(unsigned, m));
}

// ---- quantize emb -> u8 (perm (0,2,1,3), bias 128) + W2/W3 -> fp16 --------
__global__ __launch_bounds__(256) void prep_q8(
    const float4* __restrict__ emb4, unsigned* __restrict__ emb8,
    const float* __restrict__ W2, const float* __restrict__ W3,
    _Float16* __restrict__ W2h, _Float16* __restrict__ W3h,
    const unsigned* __restrict__ amax)
{
    const int i = blockIdx.x * blockDim.x + threadIdx.x;
    const float am = __builtin_bit_cast(float, *amax);
    const float qs = 127.f / am;
    if (i < 7425 * 32) {
        unsigned w = 0x80808080u;          // zero row 7424: q=0 everywhere
        if (i < 7424 * 32) {
            float4 v = emb4[i];
            int q0 = (int)rintf(v.x * qs);
            int q1 = (int)rintf(v.y * qs);
            int q2 = (int)rintf(v.z * qs);
            int q3 = (int)rintf(v.w * qs);
            q0 = min(127, max(-127, q0));
            q1 = min(127, max(-127, q1));
            q2 = min(127, max(-127, q2));
            q3 = min(127, max(-127, q3));
            // byte order (d0, d2, d1, d3): lo-mask -> dims (4j,4j+1),
            // hi-mask -> dims (4j+2,4j+3)
            w = (unsigned)(q0 + 128)
              | ((unsigned)(q2 + 128) << 8)
              | ((unsigned)(q1 + 128) << 16)
              | ((unsigned)(q3 + 128) << 24);
        }
        emb8[i] = w;
    }
    if (i < 4096) W2h[i] = (_Float16)W2[i];
    if (i < 2048) W3h[i] = (_Float16)W3[i];
}

// ---- legacy fp16 emb conversion (fallback path only) ----------------------
__global__ __launch_bounds__(256) void prep_fp16(
    const float* __restrict__ emb, __half2* __restrict__ emb16,
    int npairs_real, int npairs_tot)
{
    int i = blockIdx.x * blockDim.x + threadIdx.x;
    if (i < npairs_tot) {
        float2 v = make_float2(0.f, 0.f);
        if (i < npairs_real) v = ((const float2*)emb)[i];
        emb16[i] = __floats2half2_rn(v.x, v.y);
    }
}

// ---------------- fused kernel (int8 gather) -------------------------------
__global__ __launch_bounds__(256, 8) void nnue_one_q8(
    const int*      __restrict__ x,      // (N,32)
    const unsigned* __restrict__ emb8,   // (7425,128) u8, permuted, row 7424=128s
    const _Float16* __restrict__ W2h,    // (32,128) fp16
    const _Float16* __restrict__ W3h,    // (32,64) fp16
    const float*    __restrict__ b2,
    const float*    __restrict__ b3,
    const float*    __restrict__ W4,     // (64,)
    const unsigned* __restrict__ amax,
    float*          __restrict__ out, int n)
{
    // per-wave: hT = 16 rows x 16 uint4 (swizzled), later aliased by a2 tile
    __shared__ __align__(16) char hmem[4][4096];   // 16384 B
    // per-wave packed u16 indices: 16 rows x 32
    __shared__ __align__(16) char xmem[4][1024];   //  4096 B
    // total 20480 B -> 8 blocks/CU

    const int tid  = threadIdx.x;
    const int lane = tid & 63;
    const int wave = tid >> 6;
    const int row0 = blockIdx.x * RPB;
    const int wrow0 = __builtin_amdgcn_readfirstlane(row0 + wave * 16);

    const int f = lane >> 3;            // feature subgroup 0..7
    const int p = lane & 7;             // 16B packet in 128B row
    const unsigned pOff = (unsigned)p * 16u;

    unsigned short* xw = (unsigned short*)&xmem[wave][0];

    // ---- stage indices packed u16 (pad features 29..31 -> zero row 7424) --
    {
        const int4* xb = (const int4*)(x + (size_t)wrow0 * 32);
        int4 a = xb[lane * 2];
        int4 b = xb[lane * 2 + 1];
        if ((lane & 3) == 3) { b.y = 7424; b.z = 7424; b.w = 7424; }
        uint4 pk;
        pk.x = ((unsigned)a.x & 0xffffu) | ((unsigned)a.y << 16);
        pk.y = ((unsigned)a.z & 0xffffu) | ((unsigned)a.w << 16);
        pk.z = ((unsigned)b.x & 0xffffu) | ((unsigned)b.y << 16);
        pk.w = ((unsigned)b.z & 0xffffu) | ((unsigned)b.w << 16);
        ((uint4*)xw)[lane] = pk;
    }
    // same-wave DS ordering; no barriers anywhere in this kernel.

    const float am = __builtin_bit_cast(float, *amax);
    const float sc = am * (1.f / 127.f);
    const float cb = -4096.f * sc;      // bias removal: 32 features x 128

    // ---- gather: 4 x dwordx4 per row (int8), masked-add accumulate --------
    #pragma unroll 4
    for (int r = 0; r < 16; ++r) {
        const unsigned short* xrow = xw + r * 32 + f;
        uint4 v[4];
        #pragma unroll
        for (int b = 0; b < 4; ++b) {
            const unsigned idx = xrow[8 * b];        // ds_read_u16 broadcast
            v[b] = *(const uint4*)((const char*)emb8 + ((idx << 7) + pOff));
        }
        unsigned aL0 = 0, aL1 = 0, aL2 = 0, aL3 = 0;
        unsigned aH0 = 0, aH1 = 0, aH2 = 0, aH3 = 0;
        #pragma unroll
        for (int b = 0; b < 4; ++b) {
            aL0 += v[b].x & 0x00ff00ffu;
            aL1 += v[b].y & 0x00ff00ffu;
            aL2 += v[b].z & 0x00ff00ffu;
            aL3 += v[b].w & 0x00ff00ffu;
            aH0 += __builtin_amdgcn_perm(0u, v[b].x, 0x0c030c01u);
            aH1 += __builtin_amdgcn_perm(0u, v[b].y, 0x0c030c01u);
            aH2 += __builtin_amdgcn_perm(0u, v[b].z, 0x0c030c01u);
            aH3 += __builtin_amdgcn_perm(0u, v[b].w, 0x0c030c01u);
        }
        // butterfly allreduce across the 8 f-groups (lane bits 3,4,5)
        #pragma unroll
        for (int s = 8; s < 64; s <<= 1) {
            aL0 += (unsigned)__shfl_xor((int)aL0, s);
            aL1 += (unsigned)__shfl_xor((int)aL1, s);
            aL2 += (unsigned)__shfl_xor((int)aL2, s);
            aL3 += (unsigned)__shfl_xor((int)aL3, s);
            aH0 += (unsigned)__shfl_xor((int)aH0, s);
            aH1 += (unsigned)__shfl_xor((int)aH1, s);
            aH2 += (unsigned)__shfl_xor((int)aH2, s);
            aH3 += (unsigned)__shfl_xor((int)aH3, s);
        }
        // lane (f,p) converts one dim-pair: f<4 -> aL[f] (pair 2f),
        // f>=4 -> aH[f-4] (pair 2(f-4)+1). cndmask select, no runtime idx.
        unsigned sl  = (f & 1) ? aL1 : aL0;
        unsigned sl2 = (f & 1) ? aL3 : aL2;
        sl = (f & 2) ? sl2 : sl;
        unsigned sh  = (f & 1) ? aH1 : aH0;
        unsigned sh2 = (f & 1) ? aH3 : aH2;
        sh = (f & 2) ? sh2 : sh;
        const unsigned w = (f & 4) ? sh : sl;
        const int pi   = ((f & 3) << 1) | (f >> 2);     // pair index in segment
        const int wIdx = p * 8 + pi;                    // word 0..63 in h row
        float f0 = (float)(w & 0xffffu) * sc + cb;
        float f1 = (float)(w >> 16)     * sc + cb;
        h2v_t hv;
        hv[0] = (_Float16)fmaxf(f0, 0.f);
        hv[1] = (_Float16)fmaxf(f1, 0.f);
        const int byteOff = r * 256
                          + ((((wIdx >> 2) ^ (r & 7)) << 4) | ((wIdx & 3) << 2));
        *(unsigned*)(&hmem[wave][byteOff]) = __builtin_bit_cast(unsigned, hv);
    }

    // ================= dense (per-wave MFMA, same wave's 16 rows) ==========
    const uint4* hT = (const uint4*)&hmem[wave][0];
    const int q  = lane >> 4;     // k-quad
    const int nn = lane & 15;     // A row m / B col n / C col n

    // B-fragments for W2 (L2-hot, identical across waves)
    half8 bw2[2][4];
    #pragma unroll
    for (int nt = 0; nt < 2; ++nt)
        #pragma unroll
        for (int kk = 0; kk < 4; ++kk)
            bw2[nt][kk] = __builtin_bit_cast(half8,
                *(const uint4*)((const char*)W2h +
                    ((nt * 16 + nn) * 128 + kk * 32 + q * 8) * 2));

    // A-fragments from hT: row m = nn, packet 4*kk + q, swizzle-inverted
    half8 af[4];
    #pragma unroll
    for (int kk = 0; kk < 4; ++kk)
        af[kk] = __builtin_bit_cast(half8,
            hT[nn * 16 + ((4 * kk + q) ^ (nn & 7))]);

    // layer 2: h2(16x32) = h(16x128) @ W2^T
    f32x4 acc0 = {0.f, 0.f, 0.f, 0.f}, acc1 = {0.f, 0.f, 0.f, 0.f};
    #pragma unroll
    for (int kk = 0; kk < 4; ++kk) {
        acc0 = __builtin_amdgcn_mfma_f32_16x16x32_f16(af[kk], bw2[0][kk], acc0, 0, 0, 0);
        acc1 = __builtin_amdgcn_mfma_f32_16x16x32_f16(af[kk], bw2[1][kk], acc1, 0, 0, 0);
    }
    const float bb0 = b2[nn], bb1 = b2[16 + nn];

    // CReLU + transpose C-layout -> A-layout via LDS (stride 68 halfs).
    // a2 aliases hT: all hT (af) reads completed above, same-wave order.
    _Float16* a2 = (_Float16*)&hmem[wave][0];
    #pragma unroll
    for (int r = 0; r < 4; ++r) {
        const float v0 = acc0[r] + bb0;
        const float v1 = acc1[r] + bb1;
        const int m = q * 4 + r;
        a2[m * 68 + nn]      = (_Float16)fmaxf(v0, 0.f);
        a2[m * 68 + 16 + nn] = (_Float16)fmaxf(v1, 0.f);
        a2[m * 68 + 32 + nn] = (_Float16)fmaxf(-v0, 0.f);
        a2[m * 68 + 48 + nn] = (_Float16)fmaxf(-v1, 0.f);
    }

    // B-fragments for W3
    half8 bw3[2][2];
    #pragma unroll
    for (int nt = 0; nt < 2; ++nt)
        #pragma unroll
        for (int kk = 0; kk < 2; ++kk)
            bw3[nt][kk] = __builtin_bit_cast(half8,
                *(const uint4*)((const char*)W3h +
                    ((nt * 16 + nn) * 64 + kk * 32 + q * 8) * 2));

    // A-fragments for layer 3
    half8 a2f[2];
    #pragma unroll
    for (int kk = 0; kk < 2; ++kk) {
        const _Float16* pp = &a2[nn * 68 + kk * 32 + q * 8];
        half8 t;
        #pragma unroll
        for (int j = 0; j < 8; ++j) t[j] = pp[j];
        a2f[kk] = t;
    }

    // layer 3: h4(16x32) = crelu(h2)(16x64) @ W3^T
    f32x4 acc30 = {0.f, 0.f, 0.f, 0.f}, acc31 = {0.f, 0.f, 0.f, 0.f};
    #pragma unroll
    for (int kk = 0; kk < 2; ++kk) {
        acc30 = __builtin_amdgcn_mfma_f32_16x16x32_f16(a2f[kk], bw3[0][kk], acc30, 0, 0, 0);
        acc31 = __builtin_amdgcn_mfma_f32_16x16x32_f16(a2f[kk], bw3[1][kk], acc31, 0, 0, 0);
    }
    const float bb30 = b3[nn], bb31 = b3[16 + nn];

    // layer 4: out[m] = crelu(h4[m]) . W4
    const float w4a = W4[nn],      w4b = W4[16 + nn];
    const float w4c = W4[32 + nn], w4d = W4[48 + nn];
    float o[4];
    #pragma unroll
    for (int r = 0; r < 4; ++r) {
        const float v0 = acc30[r] + bb30;
        const float v1 = acc31[r] + bb31;
        o[r] = fmaxf(v0, 0.f) * w4a + fmaxf(-v0, 0.f) * w4c
             + fmaxf(v1, 0.f) * w4b + fmaxf(-v1, 0.f) * w4d;
    }
    #pragma unroll
    for (int s = 1; s < 16; s <<= 1) {
        #pragma unroll
        for (int r = 0; r < 4; ++r) o[r] += __shfl_xor(o[r], s);
    }
    if (nn == 0) {
        #pragma unroll
        for (int r = 0; r < 4; ++r) {
            const int row = wrow0 + q * 4 + r;
            if (row < n) out[row] = o[r];
        }
    }
}

// ---------------- fallback (R7 fused, fp32 weights) ------------------------
__global__ __launch_bounds__(256) void nnue_fused(
    const int*    __restrict__ x,
    const __half* __restrict__ emb16,
    const float*  __restrict__ W2, const float* __restrict__ b2,
    const float*  __restrict__ W3, const float* __restrict__ b3,
    const float*  __restrict__ W4,
    float*        __restrict__ out, int n)
{
    __shared__ int     xlds[4][512];
    __shared__ __half2 hbuf[64][65];
    __shared__ float   h2T[32 * 64];
    __shared__ float   obuf[4][64];

    const int tid  = threadIdx.x;
    const int lane = tid & 63;
    const int wave = tid >> 6;
    const int row0 = blockIdx.x * RPB;
    const int wrow0 = __builtin_amdgcn_readfirstlane(row0 + wave * 16);
    const int g   = lane >> 4;
    const int sub = lane & 15;
    const unsigned subOff = (unsigned)sub * 16u;

    {
        const int4* xb = (const int4*)(x + (size_t)wrow0 * 32);
        int4 a = xb[lane * 2];
        int4 b = xb[lane * 2 + 1];
        if ((lane & 3) == 3) { b.y = 7424; b.z = 7424; b.w = 7424; }
        ((int4*)&xlds[wave][0])[lane * 2]     = a;
        ((int4*)&xlds[wave][0])[lane * 2 + 1] = b;
    }

    #pragma unroll 4
    for (int r = 0; r < 16; ++r) {
        const int* xrow = &xlds[wave][r * 32 + g];
        uint4 v[8];
        #pragma unroll
        for (int b = 0; b < 8; ++b) {
            const int idx = xrow[4 * b];
            const unsigned off = ((unsigned)idx << 8) + subOff;
            v[b] = *(const uint4*)((const char*)emb16 + off);
        }
        h2v_t hacc[4];
        #pragma unroll
        for (int q = 0; q < 4; ++q) hacc[q] = (h2v_t)0;
        #pragma unroll
        for (int b = 0; b < 8; ++b) {
            hacc[0] += __builtin_bit_cast(h2v_t, v[b].x);
            hacc[1] += __builtin_bit_cast(h2v_t, v[b].y);
            hacc[2] += __builtin_bit_cast(h2v_t, v[b].z);
            hacc[3] += __builtin_bit_cast(h2v_t, v[b].w);
        }
        #pragma unroll
        for (int q = 0; q < 4; ++q) {
            unsigned u = __builtin_bit_cast(unsigned, hacc[q]);
            h2v_t t = __builtin_bit_cast(h2v_t, u);
            t += __builtin_bit_cast(h2v_t, (unsigned)__shfl_xor((int)u, 16));
            unsigned u2 = __builtin_bit_cast(unsigned, t);
            t += __builtin_bit_cast(h2v_t, (unsigned)__shfl_xor((int)u2, 32));
            hacc[q] = __builtin_elementwise_max(t, (h2v_t)0);
        }
        if (g == 0) {
            const int row = wave * 16 + r;
            #pragma unroll
            for (int q = 0; q < 4; ++q)
                hbuf[row][sub * 4 + q] = __builtin_bit_cast(__half2, hacc[q]);
        }
    }
    __syncthreads();

    {
        const int j0 = wave * 8;
        const int rr = lane;
        float acc[8];
        #pragma unroll
        for (int j = 0; j < 8; ++j) acc[j] = b2[j0 + j];
        #pragma unroll
        for (int d2 = 0; d2 < 64; ++d2) {
            const __half2 hv = hbuf[rr][d2];
            const float vx = __low2float(hv), vy = __high2float(hv);
            #pragma unroll
            for (int j = 0; j < 8; ++j) {
                const float* w = W2 + (size_t)(j0 + j) * 128 + d2 * 2;
                acc[j] = fmaf(vx, w[0], acc[j]);
                acc[j] = fmaf(vy, w[1], acc[j]);
            }
        }
        #pragma unroll
        for (int j = 0; j < 8; ++j) h2T[(j0 + j) * 64 + rr] = acc[j];
    }
    __syncthreads();

    {
        const int j0 = wave * 8;
        const int rr = lane;
        float h2v[32];
        #pragma unroll
        for (int k = 0; k < 32; ++k) h2v[k] = h2T[k * 64 + rr];
        float acc[8];
        #pragma unroll
        for (int j = 0; j < 8; ++j) acc[j] = b3[j0 + j];
        #pragma unroll
        for (int k = 0; k < 32; ++k) {
            const float pz = fmaxf(h2v[k], 0.f);
            const float mz = fmaxf(-h2v[k], 0.f);
            #pragma unroll
            for (int j = 0; j < 8; ++j) {
                const float* w = W3 + (size_t)(j0 + j) * 64;
                acc[j] = fmaf(pz, w[k],      acc[j]);
                acc[j] = fmaf(mz, w[32 + k], acc[j]);
            }
        }
        float o = 0.f;
        #pragma unroll
        for (int j = 0; j < 8; ++j) {
            const int jj = j0 + j;
            o = fmaf(fmaxf(acc[j], 0.f),  W4[jj],      o);
            o = fmaf(fmaxf(-acc[j], 0.f), W4[32 + jj], o);
        }
        obuf[wave][rr] = o;
    }
    __syncthreads();

    if (tid < 64) {
        const int row = row0 + tid;
        if (row < n)
            out[row] = obuf[0][tid] + obuf[1][tid] + obuf[2][tid] + obuf[3][tid];
    }
}

extern "C" void kernel_launch(void* const* d_in, const int* in_sizes, int n_in,
                              void* d_out, int out_size, void* d_ws, size_t ws_size,
                              hipStream_t stream) {
    const int*   x   = (const int*)  d_in[0];
    const float* emb = (const float*)d_in[1];
    const float* W2  = (const float*)d_in[2];
    const float* b2  = (const float*)d_in[3];
    const float* W3  = (const float*)d_in[4];
    const float* b3  = (const float*)d_in[5];
    const float* W4  = (const float*)d_in[6];
    float* out = (float*)d_out;
    const int n = out_size;                 // 131072 rows

    // q8 workspace layout
    const size_t emb8_bytes = (size_t)7425 * 128;           // 950,400
    const size_t w2h_off    = emb8_bytes;                   // +8192
    const size_t w3h_off    = w2h_off + 8192;               // +4096
    const size_t amax_off   = w3h_off + 4096;               // +16
    const size_t need_q8    = amax_off + 16;

    if (ws_size >= need_q8) {
        unsigned* emb8  = (unsigned*)d_ws;
        _Float16* W2h   = (_Float16*)((char*)d_ws + w2h_off);
        _Float16* W3h   = (_Float16*)((char*)d_ws + w3h_off);
        unsigned* amax  = (unsigned*)((char*)d_ws + amax_off);

        hipMemsetAsync(amax, 0, 4, stream);

        const int n4 = 7424 * 32;                           // 237,568 float4s
        hipLaunchKernelGGL(emb_absmax, dim3((n4 + 255) / 256), dim3(256),
                           0, stream, (const float4*)emb, amax, n4);

        const int nq = 7425 * 32;                           // 237,600 u32s
        hipLaunchKernelGGL(prep_q8, dim3((nq + 255) / 256), dim3(256),
                           0, stream, (const float4*)emb, emb8, W2, W3,
                           W2h, W3h, amax);

        hipLaunchKernelGGL(nnue_one_q8, dim3((n + RPB - 1) / RPB), dim3(256),
                           0, stream, x, emb8, W2h, W3h, b2, b3, W4, amax,
                           out, n);
    } else {
        // legacy fallback: fp16 table + fp32-weight fused kernel
        __half2* emb16 = (__half2*)d_ws;
        const int npairs_real = 7424 * 64;
        const int npairs_tot  = 7425 * 64;
        hipLaunchKernelGGL(prep_fp16, dim3((npairs_tot + 255) / 256), dim3(256),
                           0, stream, emb, emb16, npairs_real, npairs_tot);
        hipLaunchKernelGGL(nnue_fused, dim3((n + RPB - 1) / RPB), dim3(256),
                           0, stream, x, (const __half*)emb16, W2, b2, W3, b3,
                           W4, out, n);
    }
}